// Round 2
// baseline (172.252 us; speedup 1.0000x reference)
//
#include <hip/hip_runtime.h>

#define B_  2
#define S_  2048
#define D_  1024
#define H_  16
#define HD_ 64
#define D3_ 3072
#define NKT 16          // K-tiles (K=1024, BK=64) in the QKV gemm

typedef __bf16 bf16x8 __attribute__((ext_vector_type(8)));
typedef float  f32x4  __attribute__((ext_vector_type(4)));
typedef unsigned short u16;

__device__ __forceinline__ u16 f2bf(float f) {
  unsigned u = __float_as_uint(f);
  u += 0x7FFFu + ((u >> 16) & 1u);   // RNE
  return (u16)(u >> 16);
}

__device__ __forceinline__ f32x4 mfma16(bf16x8 a, bf16x8 b, f32x4 c) {
  return __builtin_amdgcn_mfma_f32_16x16x32_bf16(a, b, c, 0, 0, 0);
}

__device__ __forceinline__ void async16(const void* g, void* l) {
  __builtin_amdgcn_global_load_lds((const __attribute__((address_space(1))) void*)g,
                                   (__attribute__((address_space(3))) void*)l, 16, 0, 0);
}

#define GATE6  asm volatile("s_waitcnt vmcnt(6)" ::: "memory")
#define LGKM0  asm volatile("s_waitcnt lgkmcnt(0)" ::: "memory")
#define BARR   __builtin_amdgcn_s_barrier()
#define SCHED0 __builtin_amdgcn_sched_barrier(0)

// ---------------- fused prep: cast normed + transpose-cast both weights ----
__global__ void prep_k(const float* __restrict__ normed,
                       const float* __restrict__ Wqkv,
                       const float* __restrict__ Wout,
                       u16* __restrict__ nb, u16* __restrict__ wqkvT,
                       u16* __restrict__ woutT) {
  __shared__ float t[32][33];
  const int bid = blockIdx.x, tid = threadIdx.x;
  if (bid < 2048) {                       // cast f32 -> bf16, 8 elems/thread
    const int i = (bid * 256 + tid) * 8;
    float4 v0 = *(const float4*)(normed + i);
    float4 v1 = *(const float4*)(normed + i + 4);
    u16 o[8] = {f2bf(v0.x), f2bf(v0.y), f2bf(v0.z), f2bf(v0.w),
                f2bf(v1.x), f2bf(v1.y), f2bf(v1.z), f2bf(v1.w)};
    *(uint4*)(nb + i) = *(uint4*)o;
    return;
  }
  const float* in;
  u16* out;
  int R, C, bx, by;
  if (bid < 2048 + 3072) {                // Wqkv^T: [1024][3072] -> [3072][1024]
    const int tI = bid - 2048;
    in = Wqkv; out = wqkvT; R = D_; C = D3_;
    bx = (tI % 96) * 32; by = (tI / 96) * 32;
  } else {                                // Wout^T
    const int tI = bid - 5120;
    in = Wout; out = woutT; R = D_; C = D_;
    bx = (tI % 32) * 32; by = (tI / 32) * 32;
  }
  const int tx = tid & 31, ty = tid >> 5;
#pragma unroll
  for (int i = 0; i < 4; ++i)
    t[ty + i * 8][tx] = in[(size_t)(by + ty + i * 8) * C + bx + tx];
  __syncthreads();
#pragma unroll
  for (int i = 0; i < 4; ++i)
    out[(size_t)(bx + ty + i * 8) * R + by + tx] = f2bf(t[tx][ty + i * 8]);
}

// ---------------- helpers for the 8-phase 256^2 QKV gemm -------------------
__device__ __forceinline__ void read_a4(bf16x8 (&af)[4][2], const u16* base,
                                        int rbase, int quad, int l15) {
#pragma unroll
  for (int mt = 0; mt < 4; ++mt) {
    const int row = rbase + mt * 16 + l15;
#pragma unroll
    for (int ks = 0; ks < 2; ++ks)
      af[mt][ks] = *(const bf16x8*)(base + row * 64 + (((ks * 4 + quad) ^ (row & 7)) * 8));
  }
}
__device__ __forceinline__ void read_b2(bf16x8 (&bq)[2][2], const u16* base,
                                        int rbase, int quad, int l15) {
#pragma unroll
  for (int nt = 0; nt < 2; ++nt) {
    const int row = rbase + nt * 16 + l15;
#pragma unroll
    for (int ks = 0; ks < 2; ++ks)
      bq[nt][ks] = *(const bf16x8*)(base + row * 64 + (((ks * 4 + quad) ^ (row & 7)) * 8));
  }
}
__device__ __forceinline__ void quad_mfma(f32x4 (&acc)[8][4], const bf16x8 (&af)[4][2],
                                          const bf16x8 (&bq)[2][2], int mi0, int ni0) {
  __builtin_amdgcn_s_setprio(1);
#pragma unroll
  for (int mt = 0; mt < 4; ++mt)
#pragma unroll
    for (int nt = 0; nt < 2; ++nt)
#pragma unroll
      for (int ks = 0; ks < 2; ++ks)
        acc[mi0 + mt][ni0 + nt] = mfma16(af[mt][ks], bq[nt][ks], acc[mi0 + mt][ni0 + nt]);
  __builtin_amdgcn_s_setprio(0);
}

// ---------------- gemm256: QKV projection, 256x256 tile, 8-phase schedule --
// R2 fixes over R1 (42.4 us, MfmaUtil 21.8% — phase-serialization signature):
//  (a) sched_barrier(0) pins: keep ds_read+stage ISSUE above the s_barrier
//      (raw s_barrier is not an LLVM fence; compiler could sink the reads
//      to their use point, exposing full LDS latency per phase), and keep
//      MFMA below the lgkmcnt(0) (rule #18).
//  (b) read-slot rebalance 12/4/8/0 -> 4/4/8/8: A-h0 frags register-double-
//      buffered; next tile's A-h0 ds_reads issue in P4 (visibility distance
//      = 5 phases exactly: staged P3 of t-1, read P4 of t, g' = g-5 OK).
// Stage schedule unchanged from R1 (verified correct, absmax bit-identical):
//   P1: (t+1).B1   P2: (t+1).A1   P3: (t+2).A0   P4: (t+2).B0
__global__ __launch_bounds__(512, 2) void gemm256(
    const u16* __restrict__ A, const u16* __restrict__ BT,
    const float* __restrict__ bias,
    u16* __restrict__ qh, u16* __restrict__ kh, u16* __restrict__ vt) {
  extern __shared__ __align__(16) u16 smem[];   // 65536 u16 = 128 KiB
  const int tid = threadIdx.x;
  const int lane = tid & 63, w = tid >> 6;
  const int quad = lane >> 4, l15 = lane & 15;
  const int srow = lane >> 3, scol = (lane & 7) ^ srow;
  const int m0 = blockIdx.y * 256, n0 = blockIdx.x * 256;
  const int wm = (w >> 2) * 64, wn = (w & 3) * 32;

  f32x4 acc[8][4] = {};

  auto stA = [&](int ts, int half) {
    u16* dst = smem + (ts & 1) * 32768 + half * 8192;
#pragma unroll
    for (int i = 0; i < 2; ++i) {
      const int r = w * 16 + i * 8;
      async16(A + (size_t)(m0 + half * 128 + r + srow) * D_ + ts * 64 + scol * 8,
              dst + r * 64);
    }
  };
  auto stB = [&](int ts, int half) {
    u16* dst = smem + (ts & 1) * 32768 + 16384 + half * 8192;
#pragma unroll
    for (int i = 0; i < 2; ++i) {
      const int r = w * 16 + i * 8;
      async16(BT + (size_t)(n0 + half * 128 + r + srow) * D_ + ts * 64 + scol * 8,
              dst + r * 64);
    }
  };

  // prologue: 6 halves, steady-state issue order (virtual phases -6..-1)
  stA(0, 0); stB(0, 0); stB(0, 1); stA(0, 1); stA(1, 0); stB(1, 0);
  GATE6;                    // drains t0.{A0,B0,B1}; leaves 6 loads in flight
  BARR;

  bf16x8 af0[4][2], af1[4][2], bfr[2][2][2];
  read_a4(af0, smem, wm, quad, l15);          // t0 A-h0 (visible: drained above)

  for (int t = 0; t < NKT; ++t) {
    const u16* curA = smem + (t & 1) * 32768;
    const u16* curB = curA + 16384;
    const u16* nxtA = smem + ((t + 1) & 1) * 32768;
    int t1 = t + 1; if (t1 >= NKT) t1 -= 2;
    int t2 = t + 2; if (t2 >= NKT) t2 -= 2;

    // ---- P1: quadrant (mh0, nh0) ----  reads: 4
    GATE6;
    read_b2(bfr[0], curB, wn, quad, l15);      // B-h0
    stB(t1, 1);
    SCHED0;
    BARR; LGKM0; SCHED0;
    quad_mfma(acc, af0, bfr[0], 0, 0);
    BARR;

    // ---- P2: (mh0, nh1) ----  reads: 4
    GATE6;
    read_b2(bfr[1], curB, 128 + wn, quad, l15);  // B-h1
    stA(t1, 1);
    SCHED0;
    BARR; LGKM0; SCHED0;
    quad_mfma(acc, af0, bfr[1], 0, 2);
    BARR;

    // ---- P3: (mh1, nh0) ----  reads: 8
    GATE6;
    read_a4(af1, curA, 128 + wm, quad, l15);     // A-h1
    stA(t2, 0);
    SCHED0;
    BARR; LGKM0; SCHED0;
    quad_mfma(acc, af1, bfr[0], 4, 0);
    BARR;

    // ---- P4: (mh1, nh1) ----  reads: 8 (early next-tile A-h0; dist-5 safe;
    //                                     dead data on last iter, harmless)
    GATE6;
    read_a4(af0, nxtA, wm, quad, l15);
    stB(t2, 0);
    SCHED0;
    BARR; LGKM0; SCHED0;
    quad_mfma(acc, af1, bfr[1], 4, 2);
    BARR;
  }

  asm volatile("s_waitcnt vmcnt(0)" ::: "memory");  // dummy tail stages done
  __syncthreads();                                  // LDS free for epilogue

  // epilogue: block covers rows m0..m0+255 (s), cols n0..n0+255
  const int sec = n0 >> 10;        // 0=Q 1=K 2=V
  const int bsel = m0 >> 11;
  const int s_base = m0 & 2047;
  u16* lT = smem;

  if (sec < 2) {
    u16* dstb = (sec == 0) ? qh : kh;
#pragma unroll
    for (int c = 0; c < 2; ++c) {          // 128-col chunk = nh group
      if (c) __syncthreads();
#pragma unroll
      for (int mh = 0; mh < 2; ++mh)
#pragma unroll
        for (int mt = 0; mt < 4; ++mt)
#pragma unroll
          for (int nt = 0; nt < 2; ++nt) {
            const int col = wn + nt * 16 + l15;           // 0..127
            const float bv = bias[n0 + c * 128 + col];
            const int rbase = wm + mh * 128 + mt * 16 + quad * 4;
            const f32x4 a = acc[mh * 4 + mt][c * 2 + nt];
#pragma unroll
            for (int r = 0; r < 4; ++r)
              lT[(rbase + r) * 136 + col] = f2bf(a[r] + bv);
          }
      __syncthreads();
      {
        const int rr = tid >> 1, hh = tid & 1;            // 256 rows x 2 halves
        const int colglob = (n0 & 1023) + c * 128 + hh * 64;
        const int h2b = ((colglob >> 6) << 1) | bsel;
        u16* dst = dstb + ((size_t)h2b * 2048 + s_base + rr) * 64;
        const u16* src = lT + rr * 136 + hh * 64;
#pragma unroll
        for (int j = 0; j < 8; ++j)
          *(uint4*)(dst + j * 8) = *(const uint4*)(src + j * 8);
      }
    }
  } else {
#pragma unroll
    for (int c = 0; c < 2; ++c) {          // V: transpose to [h2b][kt][d][k]
      if (c) __syncthreads();
#pragma unroll
      for (int mh = 0; mh < 2; ++mh)
#pragma unroll
        for (int mt = 0; mt < 4; ++mt)
#pragma unroll
          for (int nt = 0; nt < 2; ++nt) {
            const int col = wn + nt * 16 + l15;           // 0..127 (d-chunk)
            const float bv = bias[n0 + c * 128 + col];
            const int rbase = wm + mh * 128 + mt * 16 + quad * 4;
            const f32x4 a = acc[mh * 4 + mt][c * 2 + nt];
#pragma unroll
            for (int r = 0; r < 4; ++r)
              lT[col * 264 + rbase + r] = f2bf(a[r] + bv);
          }
      __syncthreads();
      {
        const int colL = tid >> 2, ktl = tid & 3;         // 128 cols x 4 kt
        const int colglob = (n0 & 1023) + c * 128 + colL;
        const int h2b = ((colglob >> 6) << 1) | bsel;
        const int d = colglob & 63;
        const int kt0 = (s_base >> 6) + ktl;
        u16* dst = vt + (((size_t)h2b * 32 + kt0) * 64 + d) * 64;
        const u16* src = lT + colL * 264 + ktl * 64;
#pragma unroll
        for (int j = 0; j < 8; ++j)
          *(uint4*)(dst + j * 8) = *(const uint4*)(src + j * 8);
      }
    }
  }
}

// ---------------- bf16 GEMM: C = A[M][K] @ BT[N][K]^T + bias ----------------
// (used as MODE 1, MT=64 for the output projection)
template <int MODE, int MT>
__global__ __launch_bounds__(256, 3) void gemm_bt(
    const u16* __restrict__ A, const u16* __restrict__ BT,
    const float* __restrict__ bias, void* __restrict__ Cp,
    u16* __restrict__ qh, u16* __restrict__ kh, u16* __restrict__ vt,
    int M, int N, int K) {
  constexpr int SM_ELEMS = (MODE == 2) ? (128 * 136) : (MT * 64 + 128 * 64);
  __shared__ __align__(16) u16 smem[SM_ELEMS];
  u16* lA = smem;
  u16* lB = smem + MT * 64;
  const int tid = threadIdx.x;
  const int lane = tid & 63, w = tid >> 6;
  const int quad = lane >> 4, l15 = lane & 15;
  const int m0 = blockIdx.y * MT, n0 = blockIdx.x * 128;
  const int wm = (MT == 128) ? (w >> 1) * 64 : 0;
  const int wn = (MT == 128) ? (w & 1) * 64 : w * 32;
  constexpr int NF = (MT == 128) ? 4 : 2;
  constexpr int MF = 4;
  const int srow = lane >> 3;
  const int scol = (lane & 7) ^ srow;
  f32x4 acc[MF][NF] = {};

  for (int kt = 0; kt < K; kt += 64) {
    __syncthreads();
#pragma unroll
    for (int i = 0; i < MT / 32; ++i) {
      const int r = w * (MT / 4) + i * 8;
      async16(A + (size_t)(m0 + r + srow) * K + kt + scol * 8, lA + r * 64);
    }
#pragma unroll
    for (int i = 0; i < 4; ++i) {
      const int r = w * 32 + i * 8;
      async16(BT + (size_t)(n0 + r + srow) * K + kt + scol * 8, lB + r * 64);
    }
    __syncthreads();
#pragma unroll
    for (int ks = 0; ks < 2; ++ks) {
      bf16x8 af[MF], bfr[NF];
#pragma unroll
      for (int mt = 0; mt < MF; ++mt) {
        const int row = wm + mt * 16 + l15;
        const int ch = (ks * 4 + quad) ^ (row & 7);
        af[mt] = *(const bf16x8*)(lA + row * 64 + ch * 8);
      }
#pragma unroll
      for (int nt = 0; nt < NF; ++nt) {
        const int row = wn + nt * 16 + l15;
        const int ch = (ks * 4 + quad) ^ (row & 7);
        bfr[nt] = *(const bf16x8*)(lB + row * 64 + ch * 8);
      }
#pragma unroll
      for (int mt = 0; mt < MF; ++mt)
#pragma unroll
        for (int nt = 0; nt < NF; ++nt)
          acc[mt][nt] = mfma16(af[mt], bfr[nt], acc[mt][nt]);
    }
  }
  if (MODE == 1) {
#pragma unroll
    for (int nt = 0; nt < NF; ++nt) {
      const int col = n0 + wn + nt * 16 + l15;
      const float bv = bias[col];
#pragma unroll
      for (int mt = 0; mt < MF; ++mt)
#pragma unroll
        for (int r = 0; r < 4; ++r) {
          const size_t row = m0 + wm + mt * 16 + quad * 4 + r;
          ((float*)Cp)[row * N + col] = acc[mt][nt][r] + bv;
        }
    }
  }
}

// ---------------- local-causal attention, v10: BK=128 band-GEMM -----------
__global__ __launch_bounds__(256, 3) void attn_local(
    const u16* __restrict__ qh, const u16* __restrict__ kh,
    const u16* __restrict__ vt, u16* __restrict__ attno) {
  const int h2b = blockIdx.x, qc = blockIdx.y;
  const int h = h2b >> 1, b = h2b & 1;
  const int tid = threadIdx.x, lane = tid & 63, w = tid >> 6;
  const int quad = lane >> 4, l15 = lane & 15;
  const int srow = lane >> 3, scol = (lane & 7) ^ srow;
  __shared__ __align__(16) u16 lK[2][64 * 64];
  __shared__ __align__(16) u16 lV[2][64 * 64];
  __shared__ __align__(16) u16 lP[4][32 * 72];
  u16* lPw = lP[w];
  const int q0 = qc * 128, qw = q0 + w * 32;

  bf16x8 qf[2][2];
#pragma unroll
  for (int m = 0; m < 2; ++m) {
    const u16* gq = qh + ((size_t)h2b * 2048 + qw + m * 16 + l15) * 64 + quad * 8;
    qf[m][0] = *(const bf16x8*)gq;
    qf[m][1] = *(const bf16x8*)(gq + 32);
  }

  f32x4 o[2][4] = {};
  float l_r[2][4] = {{0.f, 0.f, 0.f, 0.f}, {0.f, 0.f, 0.f, 0.f}};

  const int j0 = (qc >= 2) ? 0 : 2 - qc;
  for (int j = j0; j < 3; ++j) {
    const int kg0 = qc * 2 - 4 + 2 * j;

    __syncthreads();
#pragma unroll
    for (int t = 0; t < 2; ++t) {
      const u16* gk = kh + ((size_t)h2b * 2048 + (kg0 + t) * 64) * 64;
      const u16* gv = vt + ((size_t)h2b * 32 + kg0 + t) * 4096;
#pragma unroll
      for (int i = 0; i < 2; ++i) {
        const int r = w * 16 + i * 8;
        async16(gk + (r + srow) * 64 + scol * 8, lK[t] + r * 64);
        async16(gv + (r + srow) * 64 + scol * 8, lV[t] + r * 64);
      }
    }
    __syncthreads();

#pragma unroll
    for (int t = 0; t < 2; ++t) {
      const int kg = kg0 + t;
      f32x4 s[2][4];
#pragma unroll
      for (int nt = 0; nt < 4; ++nt) {
        const int row = nt * 16 + l15;
        bf16x8 kf0 = *(const bf16x8*)(lK[t] + row * 64 + ((quad) ^ (row & 7)) * 8);
        bf16x8 kf1 = *(const bf16x8*)(lK[t] + row * 64 + ((4 + quad) ^ (row & 7)) * 8);
#pragma unroll
        for (int m = 0; m < 2; ++m) {
          f32x4 a = {};
          a = mfma16(qf[m][0], kf0, a);
          a = mfma16(qf[m][1], kf1, a);
          s[m][nt] = a;
        }
      }

#pragma unroll
      for (int m = 0; m < 2; ++m)
#pragma unroll
        for (int nt = 0; nt < 4; ++nt) {
          const int k = kg * 64 + nt * 16 + l15;
#pragma unroll
          for (int r = 0; r < 4; ++r) {
            const int q = qw + m * 16 + quad * 4 + r;
            const bool ok = (k <= q) && (k + 255 >= q);
            const float p = ok ? __expf(s[m][nt][r] * 0.125f) : 0.f;
            l_r[m][r] += p;
            lPw[(m * 16 + quad * 4 + r) * 72 + nt * 16 + l15] = f2bf(p);
          }
        }

#pragma unroll
      for (int m = 0; m < 2; ++m) {
        bf16x8 pf0 = *(const bf16x8*)(lPw + (m * 16 + l15) * 72 + quad * 8);
        bf16x8 pf1 = *(const bf16x8*)(lPw + (m * 16 + l15) * 72 + 32 + quad * 8);
#pragma unroll
        for (int nt = 0; nt < 4; ++nt) {
          const int row = nt * 16 + l15;
          bf16x8 vf0 = *(const bf16x8*)(lV[t] + row * 64 + ((quad) ^ (row & 7)) * 8);
          bf16x8 vf1 = *(const bf16x8*)(lV[t] + row * 64 + ((4 + quad) ^ (row & 7)) * 8);
          o[m][nt] = mfma16(pf0, vf0, o[m][nt]);
          o[m][nt] = mfma16(pf1, vf1, o[m][nt]);
        }
      }
    }
  }

#pragma unroll
  for (int m = 0; m < 2; ++m)
#pragma unroll
    for (int r = 0; r < 4; ++r) {
      float t = l_r[m][r];
#pragma unroll
      for (int sh = 1; sh < 16; sh <<= 1) t += __shfl_xor(t, sh);
      const int q = qw + m * 16 + quad * 4 + r;
      const float inv = 1.0f / t;
#pragma unroll
      for (int nt = 0; nt < 4; ++nt)
        attno[((size_t)b * S_ + q) * D_ + h * HD_ + nt * 16 + l15] =
            f2bf(o[m][nt][r] * inv);
    }
}

extern "C" void kernel_launch(void* const* d_in, const int* in_sizes, int n_in,
                              void* d_out, int out_size, void* d_ws, size_t ws_size,
                              hipStream_t stream) {
  (void)in_sizes; (void)n_in; (void)out_size; (void)ws_size;
  const float* normed = (const float*)d_in[0];
  // d_in[1] = attn_mask: structure known analytically, never read
  const float* Wqkv = (const float*)d_in[2];
  const float* bqkv = (const float*)d_in[3];
  const float* Wout = (const float*)d_in[4];
  const float* bout = (const float*)d_in[5];
  float* out = (float*)d_out;

  char* ws = (char*)d_ws;
  u16* nb    = (u16*)(ws);                       //  8 MB: normed bf16 [4096][1024]
  u16* wqkvT = (u16*)(ws + (8u  << 20));         //  6 MB: Wqkv^T bf16
  u16* woutT = (u16*)(ws + (14u << 20));         //  2 MB: Wout^T bf16
  u16* qh    = (u16*)(ws + (16u << 20));         //  8 MB: Q head-major [h2b][s][64]
  u16* kh    = (u16*)(ws + (24u << 20));         //  8 MB: K head-major [h2b][s][64]
  u16* vt    = (u16*)(ws + (32u << 20));         //  8 MB: V^T tiled [h2b][kt][d][k]
  u16* attno = (u16*)(ws + (40u << 20));         //  8 MB: attn out bf16

  const int M = B_ * S_;  // 4096

  static bool attr_set = false;
  if (!attr_set) {
    (void)hipFuncSetAttribute((const void*)gemm256,
                              hipFuncAttributeMaxDynamicSharedMemorySize, 131072);
    attr_set = true;
  }

  prep_k<<<6144, 256, 0, stream>>>(normed, Wqkv, Wout, nb, wqkvT, woutT);

  gemm256<<<dim3(D3_ / 256, M / 256), 512, 131072, stream>>>(
      nb, wqkvT, bqkv, qh, kh, vt);

  attn_local<<<dim3(32, 16), 256, 0, stream>>>(qh, kh, vt, attno);

  gemm_bt<1, 64><<<dim3(D_ / 128, M / 64), 256, 0, stream>>>(
      attno, woutT, bout, out, nullptr, nullptr, nullptr, M, D_, D_);
}

// Round 3
// 166.698 us; speedup vs baseline: 1.0333x; 1.0333x over previous
//
#include <hip/hip_runtime.h>

#define B_  2
#define S_  2048
#define D_  1024
#define H_  16
#define HD_ 64
#define D3_ 3072

typedef __bf16 bf16x8 __attribute__((ext_vector_type(8)));
typedef float  f32x4  __attribute__((ext_vector_type(4)));
typedef unsigned short u16;

__device__ __forceinline__ u16 f2bf(float f) {
  unsigned u = __float_as_uint(f);
  u += 0x7FFFu + ((u >> 16) & 1u);   // RNE
  return (u16)(u >> 16);
}

__device__ __forceinline__ f32x4 mfma16(bf16x8 a, bf16x8 b, f32x4 c) {
  return __builtin_amdgcn_mfma_f32_16x16x32_bf16(a, b, c, 0, 0, 0);
}

__device__ __forceinline__ void async16(const void* g, void* l) {
  __builtin_amdgcn_global_load_lds((const __attribute__((address_space(1))) void*)g,
                                   (__attribute__((address_space(3))) void*)l, 16, 0, 0);
}

// ---------------- fused prep: cast normed + transpose-cast both weights ----
// R3: transpose tiles widened to 128 input-rows x 32 input-cols so the bf16
// OUTPUT writes are 2x uint4 per thread = 256 B dense segments per 8 lanes
// (old: 32 lanes x 2 B = 64 B segments). Reads stay 128 B coalesced rows.
// LDS [128][33] f32 (pad 33 keeps the scatter write conflict-free; the pack
// read is 4-way conflicted, accepted: write-width was the bottleneck).
__global__ void prep_k(const float* __restrict__ normed,
                       const float* __restrict__ Wqkv,
                       const float* __restrict__ Wout,
                       u16* __restrict__ nb, u16* __restrict__ wqkvT,
                       u16* __restrict__ woutT) {
  __shared__ float t[128][33];
  const int bid = blockIdx.x, tid = threadIdx.x;
  if (bid < 2048) {                       // cast f32 -> bf16, 8 elems/thread
    const int i = (bid * 256 + tid) * 8;
    float4 v0 = *(const float4*)(normed + i);
    float4 v1 = *(const float4*)(normed + i + 4);
    u16 o[8] = {f2bf(v0.x), f2bf(v0.y), f2bf(v0.z), f2bf(v0.w),
                f2bf(v1.x), f2bf(v1.y), f2bf(v1.z), f2bf(v1.w)};
    *(uint4*)(nb + i) = *(uint4*)o;
    return;
  }
  const float* in;
  u16* out;
  int C, bx, by;
  if (bid < 2048 + 768) {                 // Wqkv^T: [1024][3072] -> [3072][1024]
    const int tI = bid - 2048;            // 96 col-tiles x 8 row-tiles
    in = Wqkv; out = wqkvT; C = D3_;
    bx = (tI % 96) * 32; by = (tI / 96) * 128;
  } else {                                // Wout^T: [1024][1024] -> [1024][1024]
    const int tI = bid - 2816;            // 32 col-tiles x 8 row-tiles
    in = Wout; out = woutT; C = D_;
    bx = (tI % 32) * 32; by = (tI / 32) * 128;
  }
  const int c = tid & 31, r8 = tid >> 5;  // read: row strips of 8
#pragma unroll
  for (int i = 0; i < 16; ++i) {
    const int r = i * 8 + r8;
    t[r][c] = in[(size_t)(by + r) * C + bx + c];
  }
  __syncthreads();
  const int oc = tid >> 3, og = tid & 7;  // pack: out-row oc, 16-elem group og
  u16 v[16];
#pragma unroll
  for (int k = 0; k < 16; ++k) v[k] = f2bf(t[og * 16 + k][oc]);
  u16* dst = out + (size_t)(bx + oc) * D_ + by + og * 16;
  *(uint4*)(dst)     = *(uint4*)(v);
  *(uint4*)(dst + 8) = *(uint4*)(v + 8);
}

// ---------------- bf16 GEMM: C = A[M][K] @ BT[N][K]^T + bias ----------------
// MODE 1: f32 row-major out. MODE 2 (MT=128 only): QKV split — Q/K direct
// head-major stores, V -> tiled V^T [h2b][kt][d][k] via LDS transpose.
// MT: m-tile height. MT=64 gives 2x the blocks (gemm2 was 1 block/CU ->
// fully exposed barrier drains; 2/CU lets m114 wave-overlap hide them).
// R3 note: this exact structure measured 35.5 us as gemm1 (R0); the 256^2
// 8-phase replacement ran 42-48 us across R1/R2 (no cross-wave ds||MFMA
// overlap reproduced) -> reverted per the R1 decision rule.
template <int MODE, int MT>
__global__ __launch_bounds__(256, 3) void gemm_bt(
    const u16* __restrict__ A, const u16* __restrict__ BT,
    const float* __restrict__ bias, void* __restrict__ Cp,
    u16* __restrict__ qh, u16* __restrict__ kh, u16* __restrict__ vt,
    int M, int N, int K) {
  constexpr int SM_ELEMS = (MODE == 2) ? (128 * 136) : (MT * 64 + 128 * 64);
  __shared__ __align__(16) u16 smem[SM_ELEMS];
  u16* lA = smem;
  u16* lB = smem + MT * 64;
  const int tid = threadIdx.x;
  const int lane = tid & 63, w = tid >> 6;
  const int quad = lane >> 4, l15 = lane & 15;
  const int m0 = blockIdx.y * MT, n0 = blockIdx.x * 128;
  const int wm = (MT == 128) ? (w >> 1) * 64 : 0;
  const int wn = (MT == 128) ? (w & 1) * 64 : w * 32;
  constexpr int NF = (MT == 128) ? 4 : 2;
  constexpr int MF = 4;
  const int srow = lane >> 3;
  const int scol = (lane & 7) ^ srow;
  f32x4 acc[MF][NF] = {};

  for (int kt = 0; kt < K; kt += 64) {
    __syncthreads();
#pragma unroll
    for (int i = 0; i < MT / 32; ++i) {
      const int r = w * (MT / 4) + i * 8;
      async16(A + (size_t)(m0 + r + srow) * K + kt + scol * 8, lA + r * 64);
    }
#pragma unroll
    for (int i = 0; i < 4; ++i) {
      const int r = w * 32 + i * 8;
      async16(BT + (size_t)(n0 + r + srow) * K + kt + scol * 8, lB + r * 64);
    }
    __syncthreads();
#pragma unroll
    for (int ks = 0; ks < 2; ++ks) {
      bf16x8 af[MF], bfr[NF];
#pragma unroll
      for (int mt = 0; mt < MF; ++mt) {
        const int row = wm + mt * 16 + l15;
        const int ch = (ks * 4 + quad) ^ (row & 7);
        af[mt] = *(const bf16x8*)(lA + row * 64 + ch * 8);
      }
#pragma unroll
      for (int nt = 0; nt < NF; ++nt) {
        const int row = wn + nt * 16 + l15;
        const int ch = (ks * 4 + quad) ^ (row & 7);
        bfr[nt] = *(const bf16x8*)(lB + row * 64 + ch * 8);
      }
#pragma unroll
      for (int mt = 0; mt < MF; ++mt)
#pragma unroll
        for (int nt = 0; nt < NF; ++nt)
          acc[mt][nt] = mfma16(af[mt], bfr[nt], acc[mt][nt]);
    }
  }
  // epilogue: C/D layout col=lane&15, row=quad*4+reg
  if (MODE == 1) {
#pragma unroll
    for (int nt = 0; nt < NF; ++nt) {
      const int col = n0 + wn + nt * 16 + l15;
      const float bv = bias[col];
#pragma unroll
      for (int mt = 0; mt < MF; ++mt)
#pragma unroll
        for (int r = 0; r < 4; ++r) {
          const size_t row = m0 + wm + mt * 16 + quad * 4 + r;
          ((float*)Cp)[row * N + col] = acc[mt][nt][r] + bv;
        }
    }
  } else {
    const int sec = n0 >> 10;            // block-uniform: 0=Q 1=K 2=V
    const int bsel = m0 >> 11;
    const int s_base = m0 & 2047;
    if (sec < 2) {
      u16* dstb = (sec == 0) ? qh : kh;
#pragma unroll
      for (int nt = 0; nt < NF; ++nt) {
        const int col = (n0 & 1023) + wn + nt * 16 + l15;
        const float bv = bias[n0 + wn + nt * 16 + l15];
        const int h2b = ((col >> 6) << 1) | bsel;
        const int hd = col & 63;
#pragma unroll
        for (int mt = 0; mt < MF; ++mt)
#pragma unroll
          for (int r = 0; r < 4; ++r) {
            const int s = s_base + wm + mt * 16 + quad * 4 + r;
            dstb[((size_t)h2b * 2048 + s) * 64 + hd] = f2bf(acc[mt][nt][r] + bv);
          }
      }
    } else {
      __syncthreads();                   // K-loop LDS reads done
      u16* lT = smem;
#pragma unroll
      for (int nt = 0; nt < NF; ++nt) {
        const int col_l = wn + nt * 16 + l15;
        const float bv = bias[n0 + col_l];
#pragma unroll
        for (int mt = 0; mt < MF; ++mt)
#pragma unroll
          for (int r = 0; r < 4; ++r) {
            const int row_l = wm + mt * 16 + quad * 4 + r;
            lT[col_l * 136 + row_l] = f2bf(acc[mt][nt][r] + bv);
          }
      }
      __syncthreads();
      const int rr = tid >> 1, half = tid & 1;     // 128 cols x 2 s-halves
      const int colg = (n0 & 1023) + rr;
      const int h2b = ((colg >> 6) << 1) | bsel;
      const int d = colg & 63;
      const int kt0 = (s_base >> 6) + half;
      u16* dst = vt + (((size_t)h2b * 32 + kt0) * 64 + d) * 64;
      const u16* src = lT + rr * 136 + half * 64;
#pragma unroll
      for (int j = 0; j < 8; ++j)
        *(uint4*)(dst + j * 8) = *(const uint4*)(src + j * 8);
    }
  }
}

// ---------------- local-causal attention, v10: BK=128 band-GEMM -----------
__global__ __launch_bounds__(256, 3) void attn_local(
    const u16* __restrict__ qh, const u16* __restrict__ kh,
    const u16* __restrict__ vt, u16* __restrict__ attno) {
  const int h2b = blockIdx.x, qc = blockIdx.y;
  const int h = h2b >> 1, b = h2b & 1;
  const int tid = threadIdx.x, lane = tid & 63, w = tid >> 6;
  const int quad = lane >> 4, l15 = lane & 15;
  const int srow = lane >> 3, scol = (lane & 7) ^ srow;
  __shared__ __align__(16) u16 lK[2][64 * 64];
  __shared__ __align__(16) u16 lV[2][64 * 64];
  __shared__ __align__(16) u16 lP[4][32 * 72];
  u16* lPw = lP[w];
  const int q0 = qc * 128, qw = q0 + w * 32;

  bf16x8 qf[2][2];
#pragma unroll
  for (int m = 0; m < 2; ++m) {
    const u16* gq = qh + ((size_t)h2b * 2048 + qw + m * 16 + l15) * 64 + quad * 8;
    qf[m][0] = *(const bf16x8*)gq;
    qf[m][1] = *(const bf16x8*)(gq + 32);
  }

  f32x4 o[2][4] = {};
  float l_r[2][4] = {{0.f, 0.f, 0.f, 0.f}, {0.f, 0.f, 0.f, 0.f}};

  const int j0 = (qc >= 2) ? 0 : 2 - qc;
  for (int j = j0; j < 3; ++j) {
    const int kg0 = qc * 2 - 4 + 2 * j;

    __syncthreads();
#pragma unroll
    for (int t = 0; t < 2; ++t) {
      const u16* gk = kh + ((size_t)h2b * 2048 + (kg0 + t) * 64) * 64;
      const u16* gv = vt + ((size_t)h2b * 32 + kg0 + t) * 4096;
#pragma unroll
      for (int i = 0; i < 2; ++i) {
        const int r = w * 16 + i * 8;
        async16(gk + (r + srow) * 64 + scol * 8, lK[t] + r * 64);
        async16(gv + (r + srow) * 64 + scol * 8, lV[t] + r * 64);
      }
    }
    __syncthreads();

#pragma unroll
    for (int t = 0; t < 2; ++t) {
      const int kg = kg0 + t;
      f32x4 s[2][4];
#pragma unroll
      for (int nt = 0; nt < 4; ++nt) {
        const int row = nt * 16 + l15;
        bf16x8 kf0 = *(const bf16x8*)(lK[t] + row * 64 + ((quad) ^ (row & 7)) * 8);
        bf16x8 kf1 = *(const bf16x8*)(lK[t] + row * 64 + ((4 + quad) ^ (row & 7)) * 8);
#pragma unroll
        for (int m = 0; m < 2; ++m) {
          f32x4 a = {};
          a = mfma16(qf[m][0], kf0, a);
          a = mfma16(qf[m][1], kf1, a);
          s[m][nt] = a;
        }
      }

#pragma unroll
      for (int m = 0; m < 2; ++m)
#pragma unroll
        for (int nt = 0; nt < 4; ++nt) {
          const int k = kg * 64 + nt * 16 + l15;
#pragma unroll
          for (int r = 0; r < 4; ++r) {
            const int q = qw + m * 16 + quad * 4 + r;
            const bool ok = (k <= q) && (k + 255 >= q);
            const float p = ok ? __expf(s[m][nt][r] * 0.125f) : 0.f;
            l_r[m][r] += p;
            lPw[(m * 16 + quad * 4 + r) * 72 + nt * 16 + l15] = f2bf(p);
          }
        }

#pragma unroll
      for (int m = 0; m < 2; ++m) {
        bf16x8 pf0 = *(const bf16x8*)(lPw + (m * 16 + l15) * 72 + quad * 8);
        bf16x8 pf1 = *(const bf16x8*)(lPw + (m * 16 + l15) * 72 + 32 + quad * 8);
#pragma unroll
        for (int nt = 0; nt < 4; ++nt) {
          const int row = nt * 16 + l15;
          bf16x8 vf0 = *(const bf16x8*)(lV[t] + row * 64 + ((quad) ^ (row & 7)) * 8);
          bf16x8 vf1 = *(const bf16x8*)(lV[t] + row * 64 + ((4 + quad) ^ (row & 7)) * 8);
          o[m][nt] = mfma16(pf0, vf0, o[m][nt]);
          o[m][nt] = mfma16(pf1, vf1, o[m][nt]);
        }
      }
    }
  }

#pragma unroll
  for (int m = 0; m < 2; ++m)
#pragma unroll
    for (int r = 0; r < 4; ++r) {
      float t = l_r[m][r];
#pragma unroll
      for (int sh = 1; sh < 16; sh <<= 1) t += __shfl_xor(t, sh);
      const int q = qw + m * 16 + quad * 4 + r;
      const float inv = 1.0f / t;
#pragma unroll
      for (int nt = 0; nt < 4; ++nt)
        attno[((size_t)b * S_ + q) * D_ + h * HD_ + nt * 16 + l15] =
            f2bf(o[m][nt][r] * inv);
    }
}

extern "C" void kernel_launch(void* const* d_in, const int* in_sizes, int n_in,
                              void* d_out, int out_size, void* d_ws, size_t ws_size,
                              hipStream_t stream) {
  (void)in_sizes; (void)n_in; (void)out_size; (void)ws_size;
  const float* normed = (const float*)d_in[0];
  // d_in[1] = attn_mask: structure known analytically, never read
  const float* Wqkv = (const float*)d_in[2];
  const float* bqkv = (const float*)d_in[3];
  const float* Wout = (const float*)d_in[4];
  const float* bout = (const float*)d_in[5];
  float* out = (float*)d_out;

  char* ws = (char*)d_ws;
  u16* nb    = (u16*)(ws);                       //  8 MB: normed bf16 [4096][1024]
  u16* wqkvT = (u16*)(ws + (8u  << 20));         //  6 MB: Wqkv^T bf16
  u16* woutT = (u16*)(ws + (14u << 20));         //  2 MB: Wout^T bf16
  u16* qh    = (u16*)(ws + (16u << 20));         //  8 MB: Q head-major [h2b][s][64]
  u16* kh    = (u16*)(ws + (24u << 20));         //  8 MB: K head-major [h2b][s][64]
  u16* vt    = (u16*)(ws + (32u << 20));         //  8 MB: V^T tiled [h2b][kt][d][k]
  u16* attno = (u16*)(ws + (40u << 20));         //  8 MB: attn out bf16

  const int M = B_ * S_;  // 4096

  prep_k<<<3072, 256, 0, stream>>>(normed, Wqkv, Wout, nb, wqkvT, woutT);

  gemm_bt<2, 128><<<dim3(D3_ / 128, M / 128), 256, 0, stream>>>(
      nb, wqkvT, bqkv, nullptr, qh, kh, vt, M, D3_, D_);

  attn_local<<<dim3(32, 16), 256, 0, stream>>>(qh, kh, vt, attno);

  gemm_bt<1, 64><<<dim3(D_ / 128, M / 64), 256, 0, stream>>>(
      attno, woutT, bout, out, nullptr, nullptr, nullptr, M, D_, D_);
}

// Round 4
// 158.566 us; speedup vs baseline: 1.0863x; 1.0513x over previous
//
#include <hip/hip_runtime.h>

#define B_  2
#define S_  2048
#define D_  1024
#define H_  16
#define HD_ 64
#define D3_ 3072

typedef __bf16 bf16x8 __attribute__((ext_vector_type(8)));
typedef float  f32x4  __attribute__((ext_vector_type(4)));
typedef unsigned short u16;

__device__ __forceinline__ u16 f2bf(float f) {
  unsigned u = __float_as_uint(f);
  u += 0x7FFFu + ((u >> 16) & 1u);   // RNE
  return (u16)(u >> 16);
}

__device__ __forceinline__ f32x4 mfma16(bf16x8 a, bf16x8 b, f32x4 c) {
  return __builtin_amdgcn_mfma_f32_16x16x32_bf16(a, b, c, 0, 0, 0);
}

__device__ __forceinline__ void async16(const void* g, void* l) {
  __builtin_amdgcn_global_load_lds((const __attribute__((address_space(1))) void*)g,
                                   (__attribute__((address_space(3))) void*)l, 16, 0, 0);
}

// ---------------- fused prep: cast normed + transpose-cast both weights ----
// R4: exact R0 version (R3's 128x32 rewrite regressed ~5us; reverted).
__global__ void prep_k(const float* __restrict__ normed,
                       const float* __restrict__ Wqkv,
                       const float* __restrict__ Wout,
                       u16* __restrict__ nb, u16* __restrict__ wqkvT,
                       u16* __restrict__ woutT) {
  __shared__ float t[32][33];
  const int bid = blockIdx.x, tid = threadIdx.x;
  if (bid < 2048) {                       // cast f32 -> bf16, 8 elems/thread
    const int i = (bid * 256 + tid) * 8;
    float4 v0 = *(const float4*)(normed + i);
    float4 v1 = *(const float4*)(normed + i + 4);
    u16 o[8] = {f2bf(v0.x), f2bf(v0.y), f2bf(v0.z), f2bf(v0.w),
                f2bf(v1.x), f2bf(v1.y), f2bf(v1.z), f2bf(v1.w)};
    *(uint4*)(nb + i) = *(uint4*)o;
    return;
  }
  const float* in;
  u16* out;
  int R, C, bx, by;
  if (bid < 2048 + 3072) {                // Wqkv^T: [1024][3072] -> [3072][1024]
    const int tI = bid - 2048;
    in = Wqkv; out = wqkvT; R = D_; C = D3_;
    bx = (tI % 96) * 32; by = (tI / 96) * 32;
  } else {                                // Wout^T
    const int tI = bid - 5120;
    in = Wout; out = woutT; R = D_; C = D_;
    bx = (tI % 32) * 32; by = (tI / 32) * 32;
  }
  const int tx = tid & 31, ty = tid >> 5;
#pragma unroll
  for (int i = 0; i < 4; ++i)
    t[ty + i * 8][tx] = in[(size_t)(by + ty + i * 8) * C + bx + tx];
  __syncthreads();
#pragma unroll
  for (int i = 0; i < 4; ++i)
    out[(size_t)(bx + ty + i * 8) * R + by + tx] = f2bf(t[tx][ty + i * 8]);
}

// ---------------- bf16 GEMM (QKV): C = A @ BT^T + bias, MT=128, MODE2 ------
// K-loop identical to the proven R0 structure (35.5 us). R4 change is only
// in the Q/K epilogue: scalar 2B stores (32B segments) -> LDS bounce + 8x
// uint4 per thread (16B/lane dense), same pattern the V path already uses.
__global__ __launch_bounds__(256, 3) void gemm_qkv(
    const u16* __restrict__ A, const u16* __restrict__ BT,
    const float* __restrict__ bias,
    u16* __restrict__ qh, u16* __restrict__ kh, u16* __restrict__ vt,
    int M, int N, int K) {
  constexpr int MT = 128;
  __shared__ __align__(16) u16 smem[128 * 136];
  u16* lA = smem;
  u16* lB = smem + MT * 64;
  const int tid = threadIdx.x;
  const int lane = tid & 63, w = tid >> 6;
  const int quad = lane >> 4, l15 = lane & 15;
  const int m0 = blockIdx.y * MT, n0 = blockIdx.x * 128;
  const int wm = (w >> 1) * 64;
  const int wn = (w & 1) * 64;
  constexpr int NF = 4;
  constexpr int MF = 4;
  const int srow = lane >> 3;
  const int scol = (lane & 7) ^ srow;
  f32x4 acc[MF][NF] = {};

  for (int kt = 0; kt < K; kt += 64) {
    __syncthreads();
#pragma unroll
    for (int i = 0; i < MT / 32; ++i) {
      const int r = w * (MT / 4) + i * 8;
      async16(A + (size_t)(m0 + r + srow) * K + kt + scol * 8, lA + r * 64);
    }
#pragma unroll
    for (int i = 0; i < 4; ++i) {
      const int r = w * 32 + i * 8;
      async16(BT + (size_t)(n0 + r + srow) * K + kt + scol * 8, lB + r * 64);
    }
    __syncthreads();
#pragma unroll
    for (int ks = 0; ks < 2; ++ks) {
      bf16x8 af[MF], bfr[NF];
#pragma unroll
      for (int mt = 0; mt < MF; ++mt) {
        const int row = wm + mt * 16 + l15;
        const int ch = (ks * 4 + quad) ^ (row & 7);
        af[mt] = *(const bf16x8*)(lA + row * 64 + ch * 8);
      }
#pragma unroll
      for (int nt = 0; nt < NF; ++nt) {
        const int row = wn + nt * 16 + l15;
        const int ch = (ks * 4 + quad) ^ (row & 7);
        bfr[nt] = *(const bf16x8*)(lB + row * 64 + ch * 8);
      }
#pragma unroll
      for (int mt = 0; mt < MF; ++mt)
#pragma unroll
        for (int nt = 0; nt < NF; ++nt)
          acc[mt][nt] = mfma16(af[mt], bfr[nt], acc[mt][nt]);
    }
  }
  // epilogue: C/D layout col=lane&15, row=quad*4+reg
  const int sec = n0 >> 10;            // block-uniform: 0=Q 1=K 2=V
  const int bsel = m0 >> 11;
  const int s_base = m0 & 2047;
  __syncthreads();                     // K-loop LDS reads done
  u16* lT = smem;
  if (sec < 2) {
    u16* dstb = (sec == 0) ? qh : kh;
    // stage row-major [row][col] in LDS, then dense uint4 stores
#pragma unroll
    for (int nt = 0; nt < NF; ++nt) {
      const int col_l = wn + nt * 16 + l15;
      const float bv = bias[n0 + col_l];
#pragma unroll
      for (int mt = 0; mt < MF; ++mt)
#pragma unroll
        for (int r = 0; r < 4; ++r) {
          const int row_l = wm + mt * 16 + quad * 4 + r;
          lT[row_l * 136 + col_l] = f2bf(acc[mt][nt][r] + bv);
        }
    }
    __syncthreads();
    const int rr = tid >> 1, hh = tid & 1;       // 128 s-rows x 2 head-halves
    const int colg = (n0 & 1023) + hh * 64;
    const int h2b = ((colg >> 6) << 1) | bsel;
    u16* dst = dstb + ((size_t)h2b * 2048 + s_base + rr) * 64;
    const u16* src = lT + rr * 136 + hh * 64;
#pragma unroll
    for (int j = 0; j < 8; ++j)
      *(uint4*)(dst + j * 8) = *(const uint4*)(src + j * 8);
  } else {
    // V: col-major bounce -> tiled V^T [h2b][kt][d][k]
#pragma unroll
    for (int nt = 0; nt < NF; ++nt) {
      const int col_l = wn + nt * 16 + l15;
      const float bv = bias[n0 + col_l];
#pragma unroll
      for (int mt = 0; mt < MF; ++mt)
#pragma unroll
        for (int r = 0; r < 4; ++r) {
          const int row_l = wm + mt * 16 + quad * 4 + r;
          lT[col_l * 136 + row_l] = f2bf(acc[mt][nt][r] + bv);
        }
    }
    __syncthreads();
    const int rr = tid >> 1, half = tid & 1;     // 128 cols x 2 s-halves
    const int colg = (n0 & 1023) + rr;
    const int h2b = ((colg >> 6) << 1) | bsel;
    const int d = colg & 63;
    const int kt0 = (s_base >> 6) + half;
    u16* dst = vt + (((size_t)h2b * 32 + kt0) * 64 + d) * 64;
    const u16* src = lT + rr * 136 + half * 64;
#pragma unroll
    for (int j = 0; j < 8; ++j)
      *(uint4*)(dst + j * 8) = *(const uint4*)(src + j * 8);
  }
}

// ---------------- gemm_out: out-projection, 64x128 tile, 2-phase dbuf ------
// R4: double-buffered LDS; next K-tile's global_load_lds issued BEFORE the
// current tile's compute, ONE __syncthreads per iteration (16 barriers vs
// 32). End-of-iter barrier orders last iter's reads of buf[(t+1)&1] before
// this iter's writes to it; the barrier's implicit vmcnt(0) drain makes the
// staged tile visible for the next iter. MT=64's compute-per-stage is half
// of gemm1's, so within-block staging exposure dominates -> this hides it.
__global__ __launch_bounds__(256, 3) void gemm_out(
    const u16* __restrict__ A, const u16* __restrict__ BT,
    const float* __restrict__ bias, float* __restrict__ C) {
  __shared__ __align__(16) u16 smem[2][(64 + 128) * 64];  // 2 x 24 KB
  const int tid = threadIdx.x;
  const int lane = tid & 63, w = tid >> 6;
  const int quad = lane >> 4, l15 = lane & 15;
  const int srow = lane >> 3, scol = (lane & 7) ^ srow;
  const int m0 = blockIdx.y * 64, n0 = blockIdx.x * 128;
  const int wn = w * 32;
  f32x4 acc[4][2] = {};

  auto stage = [&](int buf, int kt) {
    u16* lA = smem[buf];
    u16* lB = smem[buf] + 64 * 64;
#pragma unroll
    for (int i = 0; i < 2; ++i) {
      const int r = w * 16 + i * 8;
      async16(A + (size_t)(m0 + r + srow) * D_ + kt + scol * 8, lA + r * 64);
    }
#pragma unroll
    for (int i = 0; i < 4; ++i) {
      const int r = w * 32 + i * 8;
      async16(BT + (size_t)(n0 + r + srow) * D_ + kt + scol * 8, lB + r * 64);
    }
  };

  stage(0, 0);
  __syncthreads();                       // drains vmcnt(0): buf0 ready
  for (int t = 0; t < 16; ++t) {
    if (t < 15) stage((t + 1) & 1, (t + 1) * 64);   // fly under compute
    const u16* lA = smem[t & 1];
    const u16* lB = smem[t & 1] + 64 * 64;
#pragma unroll
    for (int ks = 0; ks < 2; ++ks) {
      bf16x8 af[4], bfr[2];
#pragma unroll
      for (int mt = 0; mt < 4; ++mt) {
        const int row = mt * 16 + l15;
        const int ch = (ks * 4 + quad) ^ (row & 7);
        af[mt] = *(const bf16x8*)(lA + row * 64 + ch * 8);
      }
#pragma unroll
      for (int nt = 0; nt < 2; ++nt) {
        const int row = wn + nt * 16 + l15;
        const int ch = (ks * 4 + quad) ^ (row & 7);
        bfr[nt] = *(const bf16x8*)(lB + row * 64 + ch * 8);
      }
#pragma unroll
      for (int mt = 0; mt < 4; ++mt)
#pragma unroll
        for (int nt = 0; nt < 2; ++nt)
          acc[mt][nt] = mfma16(af[mt], bfr[nt], acc[mt][nt]);
    }
    __syncthreads();                     // reads done + staged tile visible
  }

#pragma unroll
  for (int nt = 0; nt < 2; ++nt) {
    const int col = n0 + wn + nt * 16 + l15;
    const float bv = bias[col];
#pragma unroll
    for (int mt = 0; mt < 4; ++mt)
#pragma unroll
      for (int r = 0; r < 4; ++r) {
        const size_t row = m0 + mt * 16 + quad * 4 + r;
        C[row * D_ + col] = acc[mt][nt][r] + bv;
      }
  }
}

// ---------------- local-causal attention, v10: BK=128 band-GEMM -----------
__global__ __launch_bounds__(256, 3) void attn_local(
    const u16* __restrict__ qh, const u16* __restrict__ kh,
    const u16* __restrict__ vt, u16* __restrict__ attno) {
  const int h2b = blockIdx.x, qc = blockIdx.y;
  const int h = h2b >> 1, b = h2b & 1;
  const int tid = threadIdx.x, lane = tid & 63, w = tid >> 6;
  const int quad = lane >> 4, l15 = lane & 15;
  const int srow = lane >> 3, scol = (lane & 7) ^ srow;
  __shared__ __align__(16) u16 lK[2][64 * 64];
  __shared__ __align__(16) u16 lV[2][64 * 64];
  __shared__ __align__(16) u16 lP[4][32 * 72];
  u16* lPw = lP[w];
  const int q0 = qc * 128, qw = q0 + w * 32;

  bf16x8 qf[2][2];
#pragma unroll
  for (int m = 0; m < 2; ++m) {
    const u16* gq = qh + ((size_t)h2b * 2048 + qw + m * 16 + l15) * 64 + quad * 8;
    qf[m][0] = *(const bf16x8*)gq;
    qf[m][1] = *(const bf16x8*)(gq + 32);
  }

  f32x4 o[2][4] = {};
  float l_r[2][4] = {{0.f, 0.f, 0.f, 0.f}, {0.f, 0.f, 0.f, 0.f}};

  const int j0 = (qc >= 2) ? 0 : 2 - qc;
  for (int j = j0; j < 3; ++j) {
    const int kg0 = qc * 2 - 4 + 2 * j;

    __syncthreads();
#pragma unroll
    for (int t = 0; t < 2; ++t) {
      const u16* gk = kh + ((size_t)h2b * 2048 + (kg0 + t) * 64) * 64;
      const u16* gv = vt + ((size_t)h2b * 32 + kg0 + t) * 4096;
#pragma unroll
      for (int i = 0; i < 2; ++i) {
        const int r = w * 16 + i * 8;
        async16(gk + (r + srow) * 64 + scol * 8, lK[t] + r * 64);
        async16(gv + (r + srow) * 64 + scol * 8, lV[t] + r * 64);
      }
    }
    __syncthreads();

#pragma unroll
    for (int t = 0; t < 2; ++t) {
      const int kg = kg0 + t;
      f32x4 s[2][4];
#pragma unroll
      for (int nt = 0; nt < 4; ++nt) {
        const int row = nt * 16 + l15;
        bf16x8 kf0 = *(const bf16x8*)(lK[t] + row * 64 + ((quad) ^ (row & 7)) * 8);
        bf16x8 kf1 = *(const bf16x8*)(lK[t] + row * 64 + ((4 + quad) ^ (row & 7)) * 8);
#pragma unroll
        for (int m = 0; m < 2; ++m) {
          f32x4 a = {};
          a = mfma16(qf[m][0], kf0, a);
          a = mfma16(qf[m][1], kf1, a);
          s[m][nt] = a;
        }
      }

#pragma unroll
      for (int m = 0; m < 2; ++m)
#pragma unroll
        for (int nt = 0; nt < 4; ++nt) {
          const int k = kg * 64 + nt * 16 + l15;
#pragma unroll
          for (int r = 0; r < 4; ++r) {
            const int q = qw + m * 16 + quad * 4 + r;
            const bool ok = (k <= q) && (k + 255 >= q);
            const float p = ok ? __expf(s[m][nt][r] * 0.125f) : 0.f;
            l_r[m][r] += p;
            lPw[(m * 16 + quad * 4 + r) * 72 + nt * 16 + l15] = f2bf(p);
          }
        }

#pragma unroll
      for (int m = 0; m < 2; ++m) {
        bf16x8 pf0 = *(const bf16x8*)(lPw + (m * 16 + l15) * 72 + quad * 8);
        bf16x8 pf1 = *(const bf16x8*)(lPw + (m * 16 + l15) * 72 + 32 + quad * 8);
#pragma unroll
        for (int nt = 0; nt < 4; ++nt) {
          const int row = nt * 16 + l15;
          bf16x8 vf0 = *(const bf16x8*)(lV[t] + row * 64 + ((quad) ^ (row & 7)) * 8);
          bf16x8 vf1 = *(const bf16x8*)(lV[t] + row * 64 + ((4 + quad) ^ (row & 7)) * 8);
          o[m][nt] = mfma16(pf0, vf0, o[m][nt]);
          o[m][nt] = mfma16(pf1, vf1, o[m][nt]);
        }
      }
    }
  }

#pragma unroll
  for (int m = 0; m < 2; ++m)
#pragma unroll
    for (int r = 0; r < 4; ++r) {
      float t = l_r[m][r];
#pragma unroll
      for (int sh = 1; sh < 16; sh <<= 1) t += __shfl_xor(t, sh);
      const int q = qw + m * 16 + quad * 4 + r;
      const float inv = 1.0f / t;
#pragma unroll
      for (int nt = 0; nt < 4; ++nt)
        attno[((size_t)b * S_ + q) * D_ + h * HD_ + nt * 16 + l15] =
            f2bf(o[m][nt][r] * inv);
    }
}

extern "C" void kernel_launch(void* const* d_in, const int* in_sizes, int n_in,
                              void* d_out, int out_size, void* d_ws, size_t ws_size,
                              hipStream_t stream) {
  (void)in_sizes; (void)n_in; (void)out_size; (void)ws_size;
  const float* normed = (const float*)d_in[0];
  // d_in[1] = attn_mask: structure known analytically, never read
  const float* Wqkv = (const float*)d_in[2];
  const float* bqkv = (const float*)d_in[3];
  const float* Wout = (const float*)d_in[4];
  const float* bout = (const float*)d_in[5];
  float* out = (float*)d_out;

  char* ws = (char*)d_ws;
  u16* nb    = (u16*)(ws);                       //  8 MB: normed bf16 [4096][1024]
  u16* wqkvT = (u16*)(ws + (8u  << 20));         //  6 MB: Wqkv^T bf16
  u16* woutT = (u16*)(ws + (14u << 20));         //  2 MB: Wout^T bf16
  u16* qh    = (u16*)(ws + (16u << 20));         //  8 MB: Q head-major [h2b][s][64]
  u16* kh    = (u16*)(ws + (24u << 20));         //  8 MB: K head-major [h2b][s][64]
  u16* vt    = (u16*)(ws + (32u << 20));         //  8 MB: V^T tiled [h2b][kt][d][k]
  u16* attno = (u16*)(ws + (40u << 20));         //  8 MB: attn out bf16

  const int M = B_ * S_;  // 4096

  prep_k<<<6144, 256, 0, stream>>>(normed, Wqkv, Wout, nb, wqkvT, woutT);

  gemm_qkv<<<dim3(D3_ / 128, M / 128), 256, 0, stream>>>(
      nb, wqkvT, bqkv, qh, kh, vt, M, D3_, D_);

  attn_local<<<dim3(32, 16), 256, 0, stream>>>(qh, kh, vt, attno);

  gemm_out<<<dim3(D_ / 128, M / 64), 256, 0, stream>>>(
      attno, woutT, bout, out);
}